// Round 4
// baseline (381.590 us; speedup 1.0000x reference)
//
#include <hip/hip_runtime.h>
#include <hip/hip_bf16.h>

typedef __bf16 bf16x8 __attribute__((ext_vector_type(8)));
typedef __bf16 bf16x4 __attribute__((ext_vector_type(4)));
typedef float f32x4 __attribute__((ext_vector_type(4)));

#define B_ 2
#define L_ 2048
#define D_ 1024
#define H_ 16
#define DK_ 64

__device__ __forceinline__ __bf16 f2bf(float f) { return (__bf16)f; }

// ---------- elementwise fp32 -> bf16 ----------
__global__ __launch_bounds__(256) void cvt_bf16(const float* __restrict__ X,
                                                __bf16* __restrict__ Y) {
  const int i = (blockIdx.x * 256 + threadIdx.x) * 8;
  const float4 a = *(const float4*)&X[i];
  const float4 b = *(const float4*)&X[i + 4];
  bf16x8 o;
  o[0] = f2bf(a.x); o[1] = f2bf(a.y); o[2] = f2bf(a.z); o[3] = f2bf(a.w);
  o[4] = f2bf(b.x); o[5] = f2bf(b.y); o[6] = f2bf(b.z); o[7] = f2bf(b.w);
  *(bf16x8*)&Y[i] = o;
}

// ---------- transpose + convert: W[K,N] fp32 -> WT[N,K] bf16 ----------
__global__ __launch_bounds__(256) void transpose_cvt(const float* __restrict__ W,
                                                     __bf16* __restrict__ WT,
                                                     int K, int N) {
  __shared__ float ts[32][33];
  const int nt = blockIdx.x * 32, kt = blockIdx.y * 32;
  const int r = threadIdx.x >> 3, c4 = (threadIdx.x & 7) * 4;
  const float4 v = *(const float4*)&W[(size_t)(kt + r) * N + nt + c4];
  ts[r][c4 + 0] = v.x; ts[r][c4 + 1] = v.y; ts[r][c4 + 2] = v.z; ts[r][c4 + 3] = v.w;
  __syncthreads();
  bf16x4 o;
  o[0] = f2bf(ts[c4 + 0][r]); o[1] = f2bf(ts[c4 + 1][r]);
  o[2] = f2bf(ts[c4 + 2][r]); o[3] = f2bf(ts[c4 + 3][r]);
  *(bf16x4*)&WT[(size_t)(nt + r) * K + kt + c4] = o;
}

// ---------- m97-style GEMM: C[M,N] = A[M,K] @ BT[N,K]^T + bias ----------
// 128x128 tile, BK=32, 256 thr = 4 waves (2x2), global_load_lds width 16.
// SPLIT_V (QKV gemm): columns with (col%192)>=128 are V -> routed to
// VT[(b*H+h)*64 + d][key] instead of C (pre-transposed for attention).
template <typename TC, bool SPLIT_V>
__global__ __launch_bounds__(256) void gemm_bt(const __bf16* __restrict__ A,
                                               const __bf16* __restrict__ BT,
                                               const float* __restrict__ bias,
                                               TC* __restrict__ C,
                                               __bf16* __restrict__ VT,
                                               int M, int N, int K) {
  __shared__ __bf16 As[128 * 32];   // [m][k] contiguous (no pad: global_load_lds)
  __shared__ __bf16 Bs[128 * 32];   // [n][k] contiguous

  const int tid  = threadIdx.x;
  const int wave = tid >> 6, lane = tid & 63, quad = lane >> 4, l16 = lane & 15;
  const int wr = wave >> 1, wc = wave & 1;
  const int m0 = blockIdx.y * 128, n0 = blockIdx.x * 128;

  f32x4 acc[4][4];
#pragma unroll
  for (int i = 0; i < 4; ++i)
#pragma unroll
    for (int j = 0; j < 4; ++j) acc[i][j] = (f32x4){0.f, 0.f, 0.f, 0.f};

  for (int k0 = 0; k0 < K; k0 += 32) {
    __syncthreads();
#pragma unroll
    for (int p = 0; p < 2; ++p) {
      const int c = p * 256 + tid;          // 512 chunks of 16B per tile
      const int row = c >> 2, kc = c & 3;   // 4 chunks per 64B row
      __builtin_amdgcn_global_load_lds(
          (const __attribute__((address_space(1))) void*)&A[(size_t)(m0 + row) * K + k0 + kc * 8],
          (__attribute__((address_space(3))) void*)&As[c * 8], 16, 0, 0);
      __builtin_amdgcn_global_load_lds(
          (const __attribute__((address_space(1))) void*)&BT[(size_t)(n0 + row) * K + k0 + kc * 8],
          (__attribute__((address_space(3))) void*)&Bs[c * 8], 16, 0, 0);
    }
    __syncthreads();

    bf16x8 af[4], bfr[4];
#pragma unroll
    for (int mt = 0; mt < 4; ++mt)
      af[mt] = *(const bf16x8*)&As[(wr * 64 + mt * 16 + l16) * 32 + quad * 8];
#pragma unroll
    for (int nt = 0; nt < 4; ++nt)
      bfr[nt] = *(const bf16x8*)&Bs[(wc * 64 + nt * 16 + l16) * 32 + quad * 8];
#pragma unroll
    for (int mt = 0; mt < 4; ++mt)
#pragma unroll
      for (int nt = 0; nt < 4; ++nt)
        acc[mt][nt] = __builtin_amdgcn_mfma_f32_16x16x32_bf16(af[mt], bfr[nt], acc[mt][nt], 0, 0, 0);
  }

  // C/D: col = l16, row = quad*4 + r
#pragma unroll
  for (int nt = 0; nt < 4; ++nt) {
    const int col = n0 + wc * 64 + nt * 16 + l16;
    const float bv = bias[col];
    bool is_v = false;
    size_t vtbase = 0;
    if constexpr (SPLIT_V) {
      const int hcol = col % 192;               // uniform side per 16-col block
      if (hcol >= 128) {
        is_v = true;
        const int hh = col / 192, d = hcol - 128;
        vtbase = ((size_t)hh * DK_ + d) * L_;   // + b*H*DK*L added per row
      }
    }
#pragma unroll
    for (int mt = 0; mt < 4; ++mt)
#pragma unroll
      for (int r = 0; r < 4; ++r) {
        const int row = m0 + wr * 64 + mt * 16 + quad * 4 + r;
        const float val = acc[mt][nt][r] + bv;
        if (SPLIT_V && is_v) {
          const int bb = row >> 11, key = row & (L_ - 1);
          VT[(size_t)bb * (H_ * DK_ * L_) + vtbase + key] = f2bf(val);
        } else {
          C[(size_t)row * N + col] = (TC)val;
        }
      }
  }
}

// ---------- flash attention v3: S^T = K Q^T, zero barriers ----------
// Block 128 = 2 waves; wave owns 16 queries; key tile 64. Grid (64, H, B).
// K frags: direct global->register. V frags: direct global from VT (pre-transposed).
// P^T->A-frag via per-wave LDS (lgkmcnt only, no barrier).
__global__ __launch_bounds__(128) void attn(const __bf16* __restrict__ QKV,
                                            const __bf16* __restrict__ VT,
                                            __bf16* __restrict__ Out) {
  __shared__ __bf16 Ps[2][16][72];   // per-wave: [query][key]

  const int tid  = threadIdx.x;
  const int wave = tid >> 6, lane = tid & 63, quad = lane >> 4, l16 = lane & 15;
  const int qt = blockIdx.x, h = blockIdx.y, b = blockIdx.z;
  const size_t rowbase = (size_t)b * L_;
  const int q0 = qt * 32 + wave * 16;
  const int qcol = h * 3 * DK_;
  const int SD = 3 * D_;
  const __bf16* vt = VT + ((size_t)b * H_ + h) * (DK_ * L_);   // [d][key]

  // Q B-frags (pinned): B[k=d][n=query=l16] = Q[l16][dc*32 + quad*8 + j]
  bf16x8 qf[2];
#pragma unroll
  for (int dc = 0; dc < 2; ++dc)
    qf[dc] = *(const bf16x8*)&QKV[(rowbase + q0 + l16) * SD + qcol + dc * 32 + quad * 8];

  float m = -3.0e38f, l = 0.f;
  f32x4 o[4];
  o[0] = o[1] = o[2] = o[3] = (f32x4){0.f, 0.f, 0.f, 0.f};

  for (int kt = 0; kt < L_ / 64; ++kt) {
    const int kb = kt * 64;

    // ---- S^T = K Q^T : A = K (direct global), B = qf ----
    f32x4 st[4];
    st[0] = st[1] = st[2] = st[3] = (f32x4){0.f, 0.f, 0.f, 0.f};
#pragma unroll
    for (int kc = 0; kc < 4; ++kc) {
      const __bf16* kp = &QKV[(rowbase + kb + kc * 16 + l16) * SD + qcol + DK_ + quad * 8];
      bf16x8 a0 = *(const bf16x8*)kp;
      bf16x8 a1 = *(const bf16x8*)(kp + 32);
      st[kc] = __builtin_amdgcn_mfma_f32_16x16x32_bf16(a0, qf[0], st[kc], 0, 0, 0);
      st[kc] = __builtin_amdgcn_mfma_f32_16x16x32_bf16(a1, qf[1], st[kc], 0, 0, 0);
    }

    // ---- online softmax (lane: 16 keys of query l16) ----
    float s[16];
#pragma unroll
    for (int kc = 0; kc < 4; ++kc)
#pragma unroll
      for (int r = 0; r < 4; ++r) s[kc * 4 + r] = st[kc][r] * 0.125f;
    float mx = s[0];
#pragma unroll
    for (int i = 1; i < 16; ++i) mx = fmaxf(mx, s[i]);
    mx = fmaxf(mx, __shfl_xor(mx, 16));
    mx = fmaxf(mx, __shfl_xor(mx, 32));
    const float mnew = fmaxf(m, mx);
    const float alpha = __expf(m - mnew);
    float sum = 0.f;
#pragma unroll
    for (int i = 0; i < 16; ++i) { s[i] = __expf(s[i] - mnew); sum += s[i]; }
    sum += __shfl_xor(sum, 16);
    sum += __shfl_xor(sum, 32);
    l = l * alpha + sum;
    m = mnew;

    // P^T -> Ps[query][key]: lane holds keys kc*16+quad*4+r -> one b64 per kc
#pragma unroll
    for (int kc = 0; kc < 4; ++kc) {
      bf16x4 p4;
#pragma unroll
      for (int r = 0; r < 4; ++r) p4[r] = f2bf(s[kc * 4 + r]);
      *(bf16x4*)&Ps[wave][l16][kc * 16 + quad * 4] = p4;
    }

    // rescale O (alpha lives at query=l16; O rows are query=quad*4+r)
    float ar[4];
#pragma unroll
    for (int r = 0; r < 4; ++r) ar[r] = __shfl(alpha, quad * 4 + r);
#pragma unroll
    for (int dt = 0; dt < 4; ++dt)
#pragma unroll
      for (int r = 0; r < 4; ++r) o[dt][r] *= ar[r];

    asm volatile("s_waitcnt lgkmcnt(0)" ::: "memory");  // Ps RAW (wave-private)

    // ---- O += P V : A = Ps[l16][key], B[k=key][n=d] = VT[d][key] (global) ----
#pragma unroll
    for (int kc2 = 0; kc2 < 2; ++kc2) {
      bf16x8 pa = *(const bf16x8*)&Ps[wave][l16][kc2 * 32 + quad * 8];
#pragma unroll
      for (int dt = 0; dt < 4; ++dt) {
        bf16x8 vb = *(const bf16x8*)&vt[(size_t)(dt * 16 + l16) * L_ + kb + kc2 * 32 + quad * 8];
        o[dt] = __builtin_amdgcn_mfma_f32_16x16x32_bf16(pa, vb, o[dt], 0, 0, 0);
      }
    }
  }

  // epilogue: rows = query quad*4+r, cols = d = dt*16+l16
  float lr[4];
#pragma unroll
  for (int r = 0; r < 4; ++r) lr[r] = __shfl(l, quad * 4 + r);
#pragma unroll
  for (int dt = 0; dt < 4; ++dt)
#pragma unroll
    for (int r = 0; r < 4; ++r) {
      const size_t row = rowbase + q0 + quad * 4 + r;
      Out[row * D_ + h * DK_ + dt * 16 + l16] = f2bf(o[dt][r] / lr[r]);
    }
}

extern "C" void kernel_launch(void* const* d_in, const int* in_sizes, int n_in,
                              void* d_out, int out_size, void* d_ws, size_t ws_size,
                              hipStream_t stream) {
  (void)in_sizes; (void)n_in; (void)out_size; (void)ws_size;
  const float* x     = (const float*)d_in[0];
  const float* w_qkv = (const float*)d_in[1];
  const float* b_qkv = (const float*)d_in[2];
  const float* w_out = (const float*)d_in[3];
  const float* b_out = (const float*)d_in[4];
  float* out = (float*)d_out;

  const size_t NT = (size_t)B_ * L_;          // 4096 rows
  __bf16* qkv    = (__bf16*)d_ws;             // [4096,3072] (V region unused)
  __bf16* att    = qkv + NT * 3 * D_;         // [4096,1024]
  __bf16* xb     = att + NT * D_;             // [4096,1024]
  __bf16* wqkvT  = xb + NT * D_;              // [3072,1024]
  __bf16* woutT  = wqkvT + (size_t)3 * D_ * D_;   // [1024,1024]
  __bf16* VT     = woutT + (size_t)D_ * D_;       // [B*H*64, 2048]

  // conversions
  cvt_bf16<<<dim3((NT * D_) / 2048), dim3(256), 0, stream>>>(x, xb);
  transpose_cvt<<<dim3(3 * D_ / 32, D_ / 32), dim3(256), 0, stream>>>(w_qkv, wqkvT, D_, 3 * D_);
  transpose_cvt<<<dim3(D_ / 32, D_ / 32), dim3(256), 0, stream>>>(w_out, woutT, D_, D_);

  // QKV projection (V -> VT transposed)
  gemm_bt<__bf16, true><<<dim3(3 * D_ / 128, NT / 128), dim3(256), 0, stream>>>(
      xb, wqkvT, b_qkv, qkv, VT, (int)NT, 3 * D_, D_);
  // attention (barrier-free)
  attn<<<dim3(L_ / 32, H_, B_), dim3(128), 0, stream>>>(qkv, VT, att);
  // output projection
  gemm_bt<float, false><<<dim3(D_ / 128, NT / 128), dim3(256), 0, stream>>>(
      att, woutT, b_out, out, nullptr, (int)NT, D_, D_);
}

// Round 5
// 220.783 us; speedup vs baseline: 1.7283x; 1.7283x over previous
//
#include <hip/hip_runtime.h>
#include <hip/hip_bf16.h>

typedef __bf16 bf16x8 __attribute__((ext_vector_type(8)));
typedef __bf16 bf16x4 __attribute__((ext_vector_type(4)));
typedef float f32x4 __attribute__((ext_vector_type(4)));

#define B_ 2
#define L_ 2048
#define D_ 1024
#define H_ 16
#define DK_ 64

__device__ __forceinline__ __bf16 f2bf(float f) { return (__bf16)f; }

// ---------- elementwise fp32 -> bf16 ----------
__global__ __launch_bounds__(256) void cvt_bf16(const float* __restrict__ X,
                                                __bf16* __restrict__ Y) {
  const int i = (blockIdx.x * 256 + threadIdx.x) * 8;
  const float4 a = *(const float4*)&X[i];
  const float4 b = *(const float4*)&X[i + 4];
  bf16x8 o;
  o[0] = f2bf(a.x); o[1] = f2bf(a.y); o[2] = f2bf(a.z); o[3] = f2bf(a.w);
  o[4] = f2bf(b.x); o[5] = f2bf(b.y); o[6] = f2bf(b.z); o[7] = f2bf(b.w);
  *(bf16x8*)&Y[i] = o;
}

// ---------- transpose + convert: W[K,N] fp32 -> WT[N,K] bf16 ----------
__global__ __launch_bounds__(256) void transpose_cvt(const float* __restrict__ W,
                                                     __bf16* __restrict__ WT,
                                                     int K, int N) {
  __shared__ float ts[32][33];
  const int nt = blockIdx.x * 32, kt = blockIdx.y * 32;
  const int r = threadIdx.x >> 3, c4 = (threadIdx.x & 7) * 4;
  const float4 v = *(const float4*)&W[(size_t)(kt + r) * N + nt + c4];
  ts[r][c4 + 0] = v.x; ts[r][c4 + 1] = v.y; ts[r][c4 + 2] = v.z; ts[r][c4 + 3] = v.w;
  __syncthreads();
  bf16x4 o;
  o[0] = f2bf(ts[c4 + 0][r]); o[1] = f2bf(ts[c4 + 1][r]);
  o[2] = f2bf(ts[c4 + 2][r]); o[3] = f2bf(ts[c4 + 3][r]);
  *(bf16x4*)&WT[(size_t)(nt + r) * K + kt + c4] = o;
}

// ---------- m97-style GEMM: C[M,N] = A[M,K] @ BT[N,K]^T + bias ----------
// 128x128 tile, BK=32, 256 thr = 4 waves (2x2), global_load_lds width 16.
// SPLIT: QKV gemm — route outputs to packed per-head Qp/Kp/Vp buffers.
//   Qp[bh][tok][64]              (plain)
//   Kp[bh][tok][chunk^ (tok&7)]  (16B-chunk XOR swizzle along d)
//   Vp[bh][kt][d][chunk^(d&7)]   (64-key tiles, transposed, swizzle along key)
template <typename TC, bool SPLIT>
__global__ __launch_bounds__(256) void gemm_bt(const __bf16* __restrict__ A,
                                               const __bf16* __restrict__ BT,
                                               const float* __restrict__ bias,
                                               TC* __restrict__ C,
                                               __bf16* __restrict__ Qp,
                                               __bf16* __restrict__ Kp,
                                               __bf16* __restrict__ Vp,
                                               int M, int N, int K) {
  __shared__ __bf16 As[128 * 32];   // [m][k] contiguous (no pad: global_load_lds)
  __shared__ __bf16 Bs[128 * 32];   // [n][k] contiguous

  const int tid  = threadIdx.x;
  const int wave = tid >> 6, lane = tid & 63, quad = lane >> 4, l16 = lane & 15;
  const int wr = wave >> 1, wc = wave & 1;
  const int m0 = blockIdx.y * 128, n0 = blockIdx.x * 128;

  f32x4 acc[4][4];
#pragma unroll
  for (int i = 0; i < 4; ++i)
#pragma unroll
    for (int j = 0; j < 4; ++j) acc[i][j] = (f32x4){0.f, 0.f, 0.f, 0.f};

  for (int k0 = 0; k0 < K; k0 += 32) {
    __syncthreads();
#pragma unroll
    for (int p = 0; p < 2; ++p) {
      const int c = p * 256 + tid;          // 512 chunks of 16B per tile
      const int row = c >> 2, kc = c & 3;   // 4 chunks per 64B row
      __builtin_amdgcn_global_load_lds(
          (const __attribute__((address_space(1))) void*)&A[(size_t)(m0 + row) * K + k0 + kc * 8],
          (__attribute__((address_space(3))) void*)&As[c * 8], 16, 0, 0);
      __builtin_amdgcn_global_load_lds(
          (const __attribute__((address_space(1))) void*)&BT[(size_t)(n0 + row) * K + k0 + kc * 8],
          (__attribute__((address_space(3))) void*)&Bs[c * 8], 16, 0, 0);
    }
    __syncthreads();

    bf16x8 af[4], bfr[4];
#pragma unroll
    for (int mt = 0; mt < 4; ++mt)
      af[mt] = *(const bf16x8*)&As[(wr * 64 + mt * 16 + l16) * 32 + quad * 8];
#pragma unroll
    for (int nt = 0; nt < 4; ++nt)
      bfr[nt] = *(const bf16x8*)&Bs[(wc * 64 + nt * 16 + l16) * 32 + quad * 8];
#pragma unroll
    for (int mt = 0; mt < 4; ++mt)
#pragma unroll
      for (int nt = 0; nt < 4; ++nt)
        acc[mt][nt] = __builtin_amdgcn_mfma_f32_16x16x32_bf16(af[mt], bfr[nt], acc[mt][nt], 0, 0, 0);
  }

  // C/D: col = l16, row = quad*4 + r
#pragma unroll
  for (int nt = 0; nt < 4; ++nt) {
    const int col = n0 + wc * 64 + nt * 16 + l16;
    const float bv = bias[col];
    if constexpr (SPLIT) {
      const int hh = col / 192;        // head
      const int hcol = col % 192;      // uniform side per 16-col block
#pragma unroll
      for (int mt = 0; mt < 4; ++mt)
#pragma unroll
        for (int r = 0; r < 4; ++r) {
          const int row = m0 + wr * 64 + mt * 16 + quad * 4 + r;
          const float val = acc[mt][nt][r] + bv;
          const int bb = row >> 11, tok = row & (L_ - 1);
          const size_t bh = (size_t)bb * H_ + hh;
          if (hcol < 64) {
            Qp[(bh * L_ + tok) * 64 + hcol] = f2bf(val);
          } else if (hcol < 128) {
            const int d = hcol - 64;
            Kp[(bh * L_ + tok) * 64 + (((d >> 3) ^ (tok & 7)) << 3) + (d & 7)] = f2bf(val);
          } else {
            const int d = hcol - 128;
            Vp[bh * L_ * 64 + (size_t)(tok >> 6) * 4096 + d * 64 +
               ((((tok & 63) >> 3) ^ (d & 7)) << 3) + (tok & 7)] = f2bf(val);
          }
        }
    } else {
#pragma unroll
      for (int mt = 0; mt < 4; ++mt)
#pragma unroll
        for (int r = 0; r < 4; ++r) {
          const int row = m0 + wr * 64 + mt * 16 + quad * 4 + r;
          C[(size_t)row * N + col] = (TC)(acc[mt][nt][r] + bv);
        }
    }
  }
}

// ---------- flash attention v5: coalesced LDS staging, double-buffered ----------
// Block 256 = 4 waves; wave owns 16 queries (block = 64 q); key tile 64.
// K/V tiles are contiguous 8KB in packed global -> global_load_lds width 16.
// Fragments read via ds_read_b128 with XOR-chunk swizzle (bank-uniform).
// One barrier per key tile; next tile's DMA overlaps current compute.
__global__ __launch_bounds__(256, 4) void attn(const __bf16* __restrict__ Qp,
                                               const __bf16* __restrict__ Kp,
                                               const __bf16* __restrict__ Vp,
                                               __bf16* __restrict__ Out) {
  __shared__ __bf16 Ks[2][4096];     // [key][d] swizzled, 8KB each
  __shared__ __bf16 Vs[2][4096];     // [d][key] swizzled, 8KB each
  __shared__ __bf16 Ps[4][1024];     // per-wave P [query][key] swizzled

  const int tid  = threadIdx.x;
  const int wave = tid >> 6, lane = tid & 63, quad = lane >> 4, l16 = lane & 15;
  const int qt = blockIdx.x, h = blockIdx.y, b = blockIdx.z;
  const size_t bh = (size_t)b * H_ + h;
  const __bf16* kb = Kp + bh * (L_ * 64);
  const __bf16* vb0 = Vp + bh * (L_ * 64);
  const int q0 = qt * 64 + wave * 16;
  const int sz = l16 & 7;

  // Q B-frags (pinned): B[k=d][n=query=l16]
  bf16x8 qf[2];
#pragma unroll
  for (int dc = 0; dc < 2; ++dc)
    qf[dc] = *(const bf16x8*)&Qp[(bh * L_ + q0 + l16) * 64 + dc * 32 + quad * 8];

  float m = -3.0e38f, l = 0.f;
  f32x4 o[4];
  o[0] = o[1] = o[2] = o[3] = (f32x4){0.f, 0.f, 0.f, 0.f};

  // fixed per-lane LDS frag offsets (elements)
  const int kofs0 = l16 * 64 + ((quad ^ sz) << 3);          // K half0; half1 = ^(4<<3)
  // stage: 512 chunks of 16B per tile, 2 per thread per tensor
#define STAGE(buf, kt)                                                          \
  {                                                                             \
    _Pragma("unroll")                                                           \
    for (int p = 0; p < 2; ++p) {                                               \
      const int c = p * 256 + tid;                                              \
      __builtin_amdgcn_global_load_lds(                                         \
          (const __attribute__((address_space(1))) void*)(kb + (size_t)(kt) * 4096 + c * 8), \
          (__attribute__((address_space(3))) void*)&Ks[buf][c * 8], 16, 0, 0);  \
      __builtin_amdgcn_global_load_lds(                                         \
          (const __attribute__((address_space(1))) void*)(vb0 + (size_t)(kt) * 4096 + c * 8), \
          (__attribute__((address_space(3))) void*)&Vs[buf][c * 8], 16, 0, 0);  \
    }                                                                           \
  }

  STAGE(0, 0)
  __syncthreads();

  for (int kt = 0; kt < L_ / 64; ++kt) {
    const int cur = kt & 1;
    if (kt + 1 < L_ / 64) STAGE(cur ^ 1, kt + 1)

    const __bf16* ks = Ks[cur];
    const __bf16* vs = Vs[cur];

    // ---- S^T = K Q^T : A[m=key][k=d] from LDS, B = qf ----
    f32x4 st[4];
    st[0] = st[1] = st[2] = st[3] = (f32x4){0.f, 0.f, 0.f, 0.f};
#pragma unroll
    for (int kc = 0; kc < 4; ++kc) {
      const __bf16* kp = ks + kc * 1024 + kofs0;
      bf16x8 a0 = *(const bf16x8*)kp;
      bf16x8 a1 = *(const bf16x8*)(kp + 32);   // chunk ^4 = +4*8 elems XOR -> offset +32 or -32; ^ handled: (quad^sz)^4 chunk
      // note: ((quad^sz)^4)*8 = (quad^sz)*8 ^ 32 ; since chunks 0-7, +32 elems iff bit2 clear
      a1 = *(const bf16x8*)(ks + kc * 1024 + l16 * 64 + (((quad ^ sz) ^ 4) << 3));
      st[kc] = __builtin_amdgcn_mfma_f32_16x16x32_bf16(a0, qf[0], st[kc], 0, 0, 0);
      st[kc] = __builtin_amdgcn_mfma_f32_16x16x32_bf16(a1, qf[1], st[kc], 0, 0, 0);
    }

    // ---- online softmax (lane: keys kc*16+quad*4+r of query l16) ----
    float s[16];
#pragma unroll
    for (int kc = 0; kc < 4; ++kc)
#pragma unroll
      for (int r = 0; r < 4; ++r) s[kc * 4 + r] = st[kc][r] * 0.125f;
    float mx = s[0];
#pragma unroll
    for (int i = 1; i < 16; ++i) mx = fmaxf(mx, s[i]);
    mx = fmaxf(mx, __shfl_xor(mx, 16));
    mx = fmaxf(mx, __shfl_xor(mx, 32));
    const float mnew = fmaxf(m, mx);
    const float alpha = __expf(m - mnew);
    float sum = 0.f;
#pragma unroll
    for (int i = 0; i < 16; ++i) { s[i] = __expf(s[i] - mnew); sum += s[i]; }
    sum += __shfl_xor(sum, 16);
    sum += __shfl_xor(sum, 32);
    l = l * alpha + sum;
    m = mnew;

    // P^T -> Ps (swizzled): keys kc*16+quad*4.. -> logical chunk 2kc+(quad>>1)
#pragma unroll
    for (int kc = 0; kc < 4; ++kc) {
      bf16x4 p4;
#pragma unroll
      for (int r = 0; r < 4; ++r) p4[r] = f2bf(s[kc * 4 + r]);
      const int cl = kc * 2 + (quad >> 1);
      *(bf16x4*)&Ps[wave][l16 * 64 + ((cl ^ sz) << 3) + ((quad & 1) << 2)] = p4;
    }

    // rescale O (alpha at query=l16; O rows are query=quad*4+r)
    float ar[4];
#pragma unroll
    for (int r = 0; r < 4; ++r) ar[r] = __shfl(alpha, quad * 4 + r);
#pragma unroll
    for (int dt = 0; dt < 4; ++dt)
#pragma unroll
      for (int r = 0; r < 4; ++r) o[dt][r] *= ar[r];

    asm volatile("s_waitcnt lgkmcnt(0)" ::: "memory");  // Ps RAW (wave-private)

    // ---- O += P V : A = Ps[query=l16][key], B[k=key][n=d] = Vs[d][key] ----
#pragma unroll
    for (int kc2 = 0; kc2 < 2; ++kc2) {
      bf16x8 pa = *(const bf16x8*)&Ps[wave][l16 * 64 + (((kc2 * 4 + quad) ^ sz) << 3)];
#pragma unroll
      for (int dt = 0; dt < 4; ++dt) {
        bf16x8 vb = *(const bf16x8*)&vs[(dt * 16 + l16) * 64 + (((kc2 * 4 + quad) ^ sz) << 3)];
        o[dt] = __builtin_amdgcn_mfma_f32_16x16x32_bf16(pa, vb, o[dt], 0, 0, 0);
      }
    }

    __syncthreads();   // all waves done reading buf[cur]; buf[cur^1] DMA drained
  }

  // epilogue: rows = query quad*4+r, cols = d = dt*16+l16
  float lr[4];
#pragma unroll
  for (int r = 0; r < 4; ++r) lr[r] = __shfl(l, quad * 4 + r);
#pragma unroll
  for (int dt = 0; dt < 4; ++dt)
#pragma unroll
    for (int r = 0; r < 4; ++r) {
      const size_t row = (size_t)b * L_ + q0 + quad * 4 + r;
      Out[row * D_ + h * DK_ + dt * 16 + l16] = f2bf(o[dt][r] / lr[r]);
    }
}

extern "C" void kernel_launch(void* const* d_in, const int* in_sizes, int n_in,
                              void* d_out, int out_size, void* d_ws, size_t ws_size,
                              hipStream_t stream) {
  (void)in_sizes; (void)n_in; (void)out_size; (void)ws_size;
  const float* x     = (const float*)d_in[0];
  const float* w_qkv = (const float*)d_in[1];
  const float* b_qkv = (const float*)d_in[2];
  const float* w_out = (const float*)d_in[3];
  const float* b_out = (const float*)d_in[4];
  float* out = (float*)d_out;

  const size_t NT = (size_t)B_ * L_;              // 4096 tokens
  const size_t PHD = (size_t)B_ * H_ * L_ * 64;   // packed per-head tensor
  __bf16* att   = (__bf16*)d_ws;                  // [4096,1024]
  __bf16* xb    = att + NT * D_;                  // [4096,1024]
  __bf16* wqkvT = xb + NT * D_;                   // [3072,1024]
  __bf16* woutT = wqkvT + (size_t)3 * D_ * D_;    // [1024,1024]
  __bf16* Qp    = woutT + (size_t)D_ * D_;        // packed Q
  __bf16* Kp    = Qp + PHD;                       // packed K (swizzled)
  __bf16* Vp    = Kp + PHD;                       // packed V^T (tiled, swizzled)

  // conversions
  cvt_bf16<<<dim3((NT * D_) / 2048), dim3(256), 0, stream>>>(x, xb);
  transpose_cvt<<<dim3(3 * D_ / 32, D_ / 32), dim3(256), 0, stream>>>(w_qkv, wqkvT, D_, 3 * D_);
  transpose_cvt<<<dim3(D_ / 32, D_ / 32), dim3(256), 0, stream>>>(w_out, woutT, D_, D_);

  // QKV projection -> packed per-head Q/K/V
  gemm_bt<__bf16, true><<<dim3(3 * D_ / 128, NT / 128), dim3(256), 0, stream>>>(
      xb, wqkvT, b_qkv, (__bf16*)nullptr, Qp, Kp, Vp, (int)NT, 3 * D_, D_);
  // attention
  attn<<<dim3(L_ / 64, H_, B_), dim3(256), 0, stream>>>(Qp, Kp, Vp, att);
  // output projection
  gemm_bt<float, false><<<dim3(D_ / 128, NT / 128), dim3(256), 0, stream>>>(
      att, woutT, b_out, out, nullptr, nullptr, nullptr, (int)NT, D_, D_);
}